// Round 3
// baseline (2091.850 us; speedup 1.0000x reference)
//
#include <hip/hip_runtime.h>
#include <hip/hip_bf16.h>

#define Bc 256
#define Tc 256
#define NOBS 512
#define NACT 8
#define NST 1024
#define Gc 64
#define Xc 32
#define Pc 128
#define Hc 128

typedef unsigned short u16;
typedef unsigned int u32;
typedef __attribute__((ext_vector_type(4))) float f32x4;
typedef __attribute__((ext_vector_type(8))) short bf16x8;

__device__ __forceinline__ u16 f2bf(float f) {
    __hip_bfloat16 h = __float2bfloat16(f);
    return __builtin_bit_cast(u16, h);
}
__device__ __forceinline__ float bf2f(u16 v) {
    u32 x = ((u32)v) << 16;
    return __builtin_bit_cast(float, x);
}
__device__ __forceinline__ u32 pack2(float a, float b) {
    return (u32)f2bf(a) | (((u32)f2bf(b)) << 16);
}
__device__ __forceinline__ float dot4(f32x4 a, f32x4 b) {
    return a.x * b.x + a.y * b.y + a.z * b.z + a.w * b.w;
}

// block-wide sum of two floats over 256 threads (4 waves)
__device__ __forceinline__ void blockReduce2(float& a, float& b, volatile float* red, int tid) {
#pragma unroll
    for (int m = 1; m < 64; m <<= 1) {
        a += __shfl_xor(a, m, 64);
        b += __shfl_xor(b, m, 64);
    }
    __syncthreads();  // WAR protection on red from previous use
    if ((tid & 63) == 0) { int w = tid >> 6; red[w] = a; red[4 + w] = b; }
    __syncthreads();
    a = red[0] + red[1] + red[2] + red[3];
    b = red[4] + red[5] + red[6] + red[7];
}

// ---------------------------------------------------------------------------
// Kernel 1: fused sequential scan. One block per batch element. f32 throughout.
// M (128x128) in registers: thread (r=tid>>1, hf=tid&1) holds M[r][hf*64+0..63].
// Retrieval collapse: l2n(k*l2n(v)+M*l2n(v)) = l2n((kI+M)v)  ->
// q3 = l2n((kI+M)^3 pn), no intermediate norms.
// ---------------------------------------------------------------------------
__global__ __launch_bounds__(256, 1) void scan_kernel(
    const int* __restrict__ obs, const int* __restrict__ actions,
    const float* __restrict__ obs_emb, const float* __restrict__ act_emb,
    const float* __restrict__ g_init,
    const float* __restrict__ w_ih, const float* __restrict__ w_hh,
    const float* __restrict__ b_ih, const float* __restrict__ b_hh,
    const float* __restrict__ enc_w1, const float* __restrict__ enc_b1,
    const float* __restrict__ ln_g, const float* __restrict__ ln_b,
    const float* __restrict__ enc_w2, const float* __restrict__ enc_b2,
    float* __restrict__ outP, float* __restrict__ outPM,
    float* __restrict__ accs)
{
    int b = blockIdx.x;
    int tid = threadIdx.x;
    int r = tid >> 1, hf = tid & 1;

    __shared__ __align__(16) float aembf[NACT * Gc];
    __shared__ __align__(16) float gx[Gc + Xc];   // g(64) || x(32)
    __shared__ __align__(16) float gl[6 * Gc];    // gi(192) gh(192)
    __shared__ __align__(16) float hv[Hc];
    __shared__ __align__(16) float pnl[Pc];
    __shared__ __align__(16) float qA[Pc];
    __shared__ __align__(16) float qB[Pc];
    __shared__ __align__(16) float bihs[3 * Gc];
    __shared__ __align__(16) float bhhs[3 * Gc];
    __shared__ __align__(16) float b1s[Hc];
    __shared__ __align__(16) float lngs[Hc];
    __shared__ __align__(16) float lnbs[Hc];
    __shared__ __align__(16) float b2s[Pc];
    __shared__ float red[8];

    for (int i = tid; i < NACT * Gc; i += 256) aembf[i] = act_emb[i];
    for (int i = tid; i < 3 * Gc; i += 256) { bihs[i] = b_ih[i]; bhhs[i] = b_hh[i]; }
    if (tid < Hc) {
        b1s[tid] = enc_b1[tid];
        lngs[tid] = ln_g[tid];
        lnbs[tid] = ln_b[tid];
        b2s[tid] = enc_b2[tid];
    }
    if (tid < Gc) gx[tid] = g_init[tid];

    // weights -> registers (f32)
    float wih[64], whh[64];
    if (tid < 192) {
        const f32x4* p1 = (const f32x4*)(w_ih + tid * Gc);
        const f32x4* p2 = (const f32x4*)(w_hh + tid * Gc);
#pragma unroll
        for (int i = 0; i < 16; ++i) {
            ((f32x4*)wih)[i] = p1[i];
            ((f32x4*)whh)[i] = p2[i];
        }
    }
    float w1r[48];
    {
        const f32x4* p = (const f32x4*)(enc_w1 + r * (Gc + Xc) + hf * 48);
#pragma unroll
        for (int i = 0; i < 12; ++i) ((f32x4*)w1r)[i] = p[i];
    }
    float w2r[64];
    {
        const f32x4* p = (const f32x4*)(enc_w2 + r * Hc + hf * 64);
#pragma unroll
        for (int i = 0; i < 16; ++i) ((f32x4*)w2r)[i] = p[i];
    }

    float Mreg[64];
#pragma unroll
    for (int i = 0; i < 64; ++i) Mreg[i] = 0.f;

    float pnprev = 0.f, lmacc = 0.f;
    __syncthreads();

    for (int t = 0; t < Tc; ++t) {
        // ---- x gather (threads 224..255) ----
        int o = obs[b * Tc + t];
        if (tid >= 224) gx[Gc + tid - 224] = obs_emb[o * Xc + (tid - 224)];

        // ---- GRU gate pre-activations (threads 0..191) ----
        if (t > 0 && tid < 192) {
            int ai = actions[b * Tc + t - 1];
            const f32x4* a4 = (const f32x4*)(aembf + ai * Gc);
            const f32x4* g4 = (const f32x4*)gx;
            float s1 = bihs[tid], s2 = bhhs[tid];
#pragma unroll
            for (int m = 0; m < 16; ++m) {
                s1 += dot4(a4[m], ((const f32x4*)wih)[m]);
                s2 += dot4(g4[m], ((const f32x4*)whh)[m]);
            }
            gl[tid] = s1;
            gl[192 + tid] = s2;
        }
        __syncthreads();
        if (t > 0 && tid < Gc) {
            float ir = gl[tid], iz = gl[64 + tid], inn = gl[128 + tid];
            float hr = gl[192 + tid], hz = gl[256 + tid], hn2 = gl[320 + tid];
            float rr = 1.f / (1.f + __expf(-(ir + hr)));
            float zz = 1.f / (1.f + __expf(-(iz + hz)));
            float nn = tanhf(inn + rr * hn2);
            gx[tid] = (1.f - zz) * nn + zz * gx[tid];
        }
        __syncthreads();

        // ---- enc1 (2 threads per output row, split over 96 inputs) ----
        float hval;
        {
            const f32x4* c4 = (const f32x4*)(gx + hf * 48);
            float s = 0.f;
#pragma unroll
            for (int m = 0; m < 12; ++m) s += dot4(c4[m], ((const f32x4*)w1r)[m]);
            s += __shfl_xor(s, 1, 64);
            hval = s + b1s[r];
        }
        // LayerNorm (values duplicated x2 -> divide by 256)
        float s1 = hval, s2 = hval * hval;
        blockReduce2(s1, s2, red, tid);
        float mu = s1 * (1.f / 256.f);
        float var = s2 * (1.f / 256.f) - mu * mu;
        float hn = (hval - mu) * rsqrtf(var + 1e-5f) * lngs[r] + lnbs[r];
        hn = fmaxf(hn, 0.f);
        if (hf == 0) hv[r] = hn;
        __syncthreads();

        // ---- enc2 ----
        float pval;
        {
            const f32x4* h4 = (const f32x4*)(hv + hf * 64);
            float s = 0.f;
#pragma unroll
            for (int m = 0; m < 16; ++m) s += dot4(h4[m], ((const f32x4*)w2r)[m]);
            s += __shfl_xor(s, 1, 64);
            pval = fmaxf(s + b2s[r], 0.f) + 1e-6f;
        }
        s1 = pval * pval; s2 = 0.f;
        blockReduce2(s1, s2, red, tid);
        float pn = pval / fmaxf(sqrtf(0.5f * s1), 1e-12f);
        size_t rowoff = ((size_t)(b * Tc + t)) << 7;
        if (hf == 0) {
            pnl[r] = pn;
            qA[r] = pn;
            outP[rowoff + r] = pn;
        }
        __syncthreads();

        // ---- retrieval: q3 = N((kI+M)^3 pn) ----
        float v = 0.f;
        {
            float* qsrc = qA;
            float* qdst = qB;
#pragma unroll
            for (int it = 0; it < 3; ++it) {
                const f32x4* q4 = (const f32x4*)qsrc;
                float s = 0.f;
#pragma unroll
                for (int m = 0; m < 16; ++m) {
                    f32x4 qv = q4[hf * 16 + m];
                    s += Mreg[4 * m] * qv.x + Mreg[4 * m + 1] * qv.y +
                         Mreg[4 * m + 2] * qv.z + Mreg[4 * m + 3] * qv.w;
                }
                s += __shfl_xor(s, 1, 64);
                v = 0.8f * qsrc[r] + s;
                if (it < 2) {
                    if (hf == 0) qdst[r] = v;
                    __syncthreads();
                    float* tmp = qsrc; qsrc = qdst; qdst = tmp;
                }
            }
        }
        float pnr = pnl[r];
        s1 = v * v; s2 = 0.f;
        blockReduce2(s1, s2, red, tid);
        float n3 = fmaxf(sqrtf(0.5f * s1), 1e-12f);
        float pm = v / n3;
        if (hf == 0) outPM[rowoff + r] = pm;
        if (t > 0) { float d = pm - pnprev; lmacc += d * d; }
        pnprev = pn;

        // ---- M update: M = 0.995*M + 0.4*pn pn^T (registers) ----
        {
            float cc = 0.4f * pnr;
            const f32x4* p4 = (const f32x4*)pnl;
#pragma unroll
            for (int m = 0; m < 16; ++m) {
                f32x4 pv = p4[hf * 16 + m];
                Mreg[4 * m]     = 0.995f * Mreg[4 * m]     + cc * pv.x;
                Mreg[4 * m + 1] = 0.995f * Mreg[4 * m + 1] + cc * pv.y;
                Mreg[4 * m + 2] = 0.995f * Mreg[4 * m + 2] + cc * pv.z;
                Mreg[4 * m + 3] = 0.995f * Mreg[4 * m + 3] + cc * pv.w;
            }
        }
    }

    float dummy = 0.f;
    blockReduce2(lmacc, dummy, red, tid);
    if (tid == 0) atomicAdd(&accs[2], 0.5f * lmacc);  // values duplicated x2
}

// ---------------------------------------------------------------------------
// Kernel 2: decoder GEMM, f32 in/out, bf16 MFMA inside.
// V[row,:] = pn[row,:] + pm[row,:];  C[row,col] = (V . W[col,:]) / ||V_row|| + b.
// blockIdx.x: 0..3 obs col-tiles, 4..11 state col-tiles. 128x128 tile,
// 4 waves of 64x64, mfma 16x16x32 bf16.
// ---------------------------------------------------------------------------
__global__ __launch_bounds__(256, 2) void dec_gemm(
    const float* __restrict__ pn_, const float* __restrict__ pm_,
    const float* __restrict__ wo, const float* __restrict__ bo,
    const float* __restrict__ wsd, const float* __restrict__ bsd,
    float* __restrict__ outO, float* __restrict__ outS)
{
    __shared__ u16 As[128 * 136];
    __shared__ u16 Bs[128 * 136];
    __shared__ float rnorm[128];
    int cb = blockIdx.x;
    int rowbase = blockIdx.y * 128;
    const float* W; const float* bias; float* out; int Nw; int colbase;
    if (cb < 4) { W = wo; bias = bo; out = outO; Nw = 512; colbase = cb * 128; }
    else        { W = wsd; bias = bsd; out = outS; Nw = 1024; colbase = (cb - 4) * 128; }
    int tid = threadIdx.x;
    for (int i = tid; i < 2048; i += 256) {
        int row = i >> 4, kb = i & 15;
        size_t go = ((size_t)(rowbase + row)) * 128 + kb * 8;
        f32x4 a0 = *(const f32x4*)(pn_ + go);
        f32x4 a1 = *(const f32x4*)(pn_ + go + 4);
        f32x4 m0v = *(const f32x4*)(pm_ + go);
        f32x4 m1v = *(const f32x4*)(pm_ + go + 4);
        f32x4 v0 = a0 + m0v, v1 = a1 + m1v;
        uint4 vv;
        vv.x = pack2(v0.x, v0.y); vv.y = pack2(v0.z, v0.w);
        vv.z = pack2(v1.x, v1.y); vv.w = pack2(v1.z, v1.w);
        *(uint4*)(As + row * 136 + kb * 8) = vv;
        size_t gw = ((size_t)(colbase + row)) * 128 + kb * 8;
        f32x4 w0 = *(const f32x4*)(W + gw);
        f32x4 w1 = *(const f32x4*)(W + gw + 4);
        uint4 wv;
        wv.x = pack2(w0.x, w0.y); wv.y = pack2(w0.z, w0.w);
        wv.z = pack2(w1.x, w1.y); wv.w = pack2(w1.z, w1.w);
        *(uint4*)(Bs + row * 136 + kb * 8) = wv;
    }
    __syncthreads();
    // per-row 1/||V|| from the staged (bf16-rounded) values
    {
        int rr = tid >> 1, hh = tid & 1;
        const u16* rowp = As + rr * 136 + hh * 64;
        float ss = 0.f;
#pragma unroll
        for (int i = 0; i < 64; ++i) { float x = bf2f(rowp[i]); ss += x * x; }
        ss += __shfl_xor(ss, 1, 64);
        if (hh == 0) rnorm[rr] = 1.f / fmaxf(sqrtf(ss), 1e-12f);
    }
    __syncthreads();
    int wv_ = tid >> 6, lane = tid & 63;
    int m0 = (wv_ & 1) * 64, n0 = (wv_ >> 1) * 64;
    int lr = lane & 15, lq = lane >> 4;
    const f32x4 vzero = {0.f, 0.f, 0.f, 0.f};
    f32x4 acc[4][4];
#pragma unroll
    for (int a = 0; a < 4; ++a)
#pragma unroll
        for (int c = 0; c < 4; ++c) acc[a][c] = vzero;
#pragma unroll
    for (int ks = 0; ks < 4; ++ks) {
        bf16x8 af[4], bfr[4];
#pragma unroll
        for (int i = 0; i < 4; ++i) {
            af[i]  = *(const bf16x8*)(As + (m0 + i * 16 + lr) * 136 + ks * 32 + lq * 8);
            bfr[i] = *(const bf16x8*)(Bs + (n0 + i * 16 + lr) * 136 + ks * 32 + lq * 8);
        }
#pragma unroll
        for (int mi = 0; mi < 4; ++mi)
#pragma unroll
            for (int ni = 0; ni < 4; ++ni)
                acc[mi][ni] = __builtin_amdgcn_mfma_f32_16x16x32_bf16(af[mi], bfr[ni], acc[mi][ni], 0, 0, 0);
    }
#pragma unroll
    for (int ni = 0; ni < 4; ++ni) {
        int col = colbase + n0 + ni * 16 + lr;
        float bb = bias[col];
#pragma unroll
        for (int mi = 0; mi < 4; ++mi) {
            int rloc = m0 + mi * 16 + lq * 4;
            int row = rowbase + rloc;
#pragma unroll
            for (int k2 = 0; k2 < 4; ++k2) {
                out[((size_t)(row + k2)) * Nw + col] = acc[mi][ni][k2] * rnorm[rloc + k2] + bb;
            }
        }
    }
}

// ---------------------------------------------------------------------------
// Kernel 3: per-row logsumexp CE losses, f32 logits. One wave per row.
// ---------------------------------------------------------------------------
__global__ __launch_bounds__(256) void loss_rows(
    const float* __restrict__ lo_, const float* __restrict__ ls_,
    const int* __restrict__ obs, const int* __restrict__ states,
    float* __restrict__ accs)
{
    __shared__ float part[8];
    int wv = threadIdx.x >> 6, lane = threadIdx.x & 63;
    float accO = 0.f, accS = 0.f;
    int rowbase = blockIdx.x * 128 + wv * 32;
    for (int i = 0; i < 32; ++i) {
        int row = rowbase + i;
        {
            const float* ro = lo_ + ((size_t)row << 9);
            f32x4 u0 = *(const f32x4*)(ro + lane * 8);
            f32x4 u1 = *(const f32x4*)(ro + lane * 8 + 4);
            float m = fmaxf(fmaxf(fmaxf(u0.x, u0.y), fmaxf(u0.z, u0.w)),
                            fmaxf(fmaxf(u1.x, u1.y), fmaxf(u1.z, u1.w)));
#pragma unroll
            for (int k = 1; k < 64; k <<= 1) m = fmaxf(m, __shfl_xor(m, k, 64));
            float se = __expf(u0.x - m) + __expf(u0.y - m) + __expf(u0.z - m) + __expf(u0.w - m) +
                       __expf(u1.x - m) + __expf(u1.y - m) + __expf(u1.z - m) + __expf(u1.w - m);
#pragma unroll
            for (int k = 1; k < 64; k <<= 1) se += __shfl_xor(se, k, 64);
            float lse = m + __logf(se);
            float xt = ro[obs[row]];
            if (lane == 0) accO += lse - xt;
        }
        {
            const float* rs = ls_ + ((size_t)row << 10);
            f32x4 u0 = *(const f32x4*)(rs + lane * 16);
            f32x4 u1 = *(const f32x4*)(rs + lane * 16 + 4);
            f32x4 u2 = *(const f32x4*)(rs + lane * 16 + 8);
            f32x4 u3 = *(const f32x4*)(rs + lane * 16 + 12);
            float m = fmaxf(fmaxf(fmaxf(u0.x, u0.y), fmaxf(u0.z, u0.w)),
                            fmaxf(fmaxf(u1.x, u1.y), fmaxf(u1.z, u1.w)));
            m = fmaxf(m, fmaxf(fmaxf(fmaxf(u2.x, u2.y), fmaxf(u2.z, u2.w)),
                               fmaxf(fmaxf(u3.x, u3.y), fmaxf(u3.z, u3.w))));
#pragma unroll
            for (int k = 1; k < 64; k <<= 1) m = fmaxf(m, __shfl_xor(m, k, 64));
            float se = __expf(u0.x - m) + __expf(u0.y - m) + __expf(u0.z - m) + __expf(u0.w - m) +
                       __expf(u1.x - m) + __expf(u1.y - m) + __expf(u1.z - m) + __expf(u1.w - m) +
                       __expf(u2.x - m) + __expf(u2.y - m) + __expf(u2.z - m) + __expf(u2.w - m) +
                       __expf(u3.x - m) + __expf(u3.y - m) + __expf(u3.z - m) + __expf(u3.w - m);
#pragma unroll
            for (int k = 1; k < 64; k <<= 1) se += __shfl_xor(se, k, 64);
            float lse = m + __logf(se);
            float xt = rs[states[row]];
            if (lane == 0) accS += lse - xt;
        }
    }
    if (lane == 0) { part[wv] = accO; part[4 + wv] = accS; }
    __syncthreads();
    if (threadIdx.x == 0) {
        atomicAdd(&accs[0], part[0] + part[1] + part[2] + part[3]);
        atomicAdd(&accs[1], part[4] + part[5] + part[6] + part[7]);
    }
}

__global__ void finalize_kernel(const float* __restrict__ accs, float* __restrict__ out_loss)
{
    float lo = accs[0] * (1.f / 65536.f);
    float ls = accs[1] * (1.f / 65536.f);
    float lm = accs[2] * (1.f / (256.f * 255.f * 128.f));
    out_loss[0] = lo + 0.1f * lm + ls;
}

extern "C" void kernel_launch(void* const* d_in, const int* in_sizes, int n_in,
                              void* d_out, int out_size, void* d_ws, size_t ws_size,
                              hipStream_t stream)
{
    const int* obs        = (const int*)d_in[0];
    const int* actions    = (const int*)d_in[1];
    const int* states     = (const int*)d_in[2];
    const float* obs_emb  = (const float*)d_in[3];
    const float* act_emb  = (const float*)d_in[4];
    const float* g_init   = (const float*)d_in[5];
    const float* w_ih     = (const float*)d_in[6];
    const float* w_hh     = (const float*)d_in[7];
    const float* b_ih     = (const float*)d_in[8];
    const float* b_hh     = (const float*)d_in[9];
    const float* enc_w1   = (const float*)d_in[10];
    const float* enc_b1   = (const float*)d_in[11];
    const float* ln_g     = (const float*)d_in[12];
    const float* ln_b     = (const float*)d_in[13];
    const float* enc_w2   = (const float*)d_in[14];
    const float* enc_b2   = (const float*)d_in[15];
    const float* dec_obs_w = (const float*)d_in[16];
    const float* dec_obs_b = (const float*)d_in[17];
    const float* dec_st_w  = (const float*)d_in[18];
    const float* dec_st_b  = (const float*)d_in[19];

    float* out = (float*)d_out;
    float* outO    = out;                            // (B,T,512)
    float* outS    = out + (size_t)33554432;         // (B,T,1024)
    float* outP    = out + (size_t)100663296;        // (B,T,128) p_norm
    float* outPM   = out + (size_t)109051904;        // (B,T,128) p_mem
    float* outLoss = out + (size_t)117440512;        // scalar

    float* accs = (float*)d_ws;  // [0]=obs CE sum [1]=state CE sum [2]=mem MSE sum

    hipMemsetAsync(d_ws, 0, 64, stream);
    scan_kernel<<<dim3(256), dim3(256), 0, stream>>>(
        obs, actions, obs_emb, act_emb, g_init, w_ih, w_hh, b_ih, b_hh,
        enc_w1, enc_b1, ln_g, ln_b, enc_w2, enc_b2, outP, outPM, accs);
    dec_gemm<<<dim3(12, 512), dim3(256), 0, stream>>>(
        outP, outPM, dec_obs_w, dec_obs_b, dec_st_w, dec_st_b, outO, outS);
    loss_rows<<<dim3(512), dim3(256), 0, stream>>>(outO, outS, obs, states, accs);
    finalize_kernel<<<dim3(1), dim3(1), 0, stream>>>(accs, outLoss);
}